// Round 4
// baseline (509.128 us; speedup 1.0000x reference)
//
#include <hip/hip_runtime.h>
#include <hip/hip_bf16.h>

#define TT 2048
#define CC 2048
#define HH 16
#define HS 128
#define BB 2
#define MM (BB*TT)   // 4096

typedef __attribute__((ext_vector_type(8))) short bf16x8;
typedef __attribute__((ext_vector_type(4))) short bf16x4;
typedef __attribute__((ext_vector_type(4))) float f32x4;

__device__ __forceinline__ short f2bf(float x) {
    unsigned u = __float_as_uint(x);
    unsigned r = (u + 0x7FFFu + ((u >> 16) & 1u)) >> 16;
    return (short)r;
}

// direct global -> LDS async copy, 16B per lane (dest must be wave-uniform base + lane*16)
__device__ __forceinline__ void gl_lds16(const void* g, void* l) {
    __builtin_amdgcn_global_load_lds(
        (const __attribute__((address_space(1))) unsigned int*)g,
        (__attribute__((address_space(3))) unsigned int*)l,
        16, 0, 0);
}

// ---------------- fp32 -> bf16 convert (idx) ----------------
__global__ void cvt_bf16_kernel(const float* __restrict__ x, short* __restrict__ y, int n) {
    int stride = gridDim.x * blockDim.x;
    for (int i = blockIdx.x * blockDim.x + threadIdx.x; i < n/4; i += stride) {
        float4 v = reinterpret_cast<const float4*>(x)[i];
        bf16x4 s;
        s[0] = f2bf(v.x); s[1] = f2bf(v.y); s[2] = f2bf(v.z); s[3] = f2bf(v.w);
        reinterpret_cast<bf16x4*>(y)[i] = s;
    }
}

// ---------------- W [k][n] fp32  ->  Wt [n][k] bf16 ----------------
__global__ void wt_kernel(const float* __restrict__ w0, const float* __restrict__ w1,
                          const float* __restrict__ w2, const float* __restrict__ w3,
                          short* __restrict__ o0, short* __restrict__ o1,
                          short* __restrict__ o2, short* __restrict__ o3)
{
    const float* W; short* Wt;
    switch (blockIdx.z) {
        case 0:  W = w0; Wt = o0; break;
        case 1:  W = w1; Wt = o1; break;
        case 2:  W = w2; Wt = o2; break;
        default: W = w3; Wt = o3; break;
    }
    __shared__ float tile[32][33];
    int tx = threadIdx.x, ty = threadIdx.y;           // block (32,8)
    int k0 = blockIdx.x * 32, n0 = blockIdx.y * 32;
    #pragma unroll
    for (int i = 0; i < 4; ++i)
        tile[ty + i*8][tx] = W[(size_t)(k0 + ty + i*8) * CC + n0 + tx];
    __syncthreads();
    #pragma unroll
    for (int i = 0; i < 4; ++i)
        Wt[(size_t)(n0 + ty + i*8) * CC + k0 + tx] = f2bf(tile[tx][ty + i*8]);
}

// ---------------- GEMM: C[M][N] = A[M][K] * Bt[N][K]^T (+bias, *scale) ----------------
// MODE 0: dst = bf16 [B,H,T,hs] (Q/K);  MODE 1: dst = fp32 [M][N];  MODE 2: dst = bf16 [B,H,hs,T] (V transposed)
template<int MODE>
__launch_bounds__(256)
__global__ void gemm_bt_kernel(const short* __restrict__ A, const short* __restrict__ Bt,
                               const float* __restrict__ bias, void* __restrict__ dst,
                               float scale)
{
    __shared__ __align__(16) short As[128*64];
    __shared__ __align__(16) short Bs[128*64];
    const int tid = threadIdx.x;
    const int lane = tid & 63;
    const int g = lane >> 4, fr = lane & 15;
    const int wid = tid >> 6;
    const int wr = wid >> 1, wc = wid & 1;
    const int m0 = blockIdx.x * 128, n0 = blockIdx.y * 128;

    f32x4 acc[4][4];
    #pragma unroll
    for (int i = 0; i < 4; ++i)
        #pragma unroll
        for (int j = 0; j < 4; ++j) acc[i][j] = (f32x4){0.f,0.f,0.f,0.f};

    for (int k0 = 0; k0 < CC; k0 += 64) {
        __syncthreads();
        // async stage A/B tiles: linear LDS dest, pre-swizzled global source
        #pragma unroll
        for (int i = 0; i < 4; ++i) {
            int c = i*256 + tid;
            int row = c >> 3;
            int kbl = ((c & 7) * 16) ^ ((row & 7) << 4);
            gl_lds16(reinterpret_cast<const char*>(A) + ((size_t)(m0+row)*CC + k0)*2 + kbl,
                     reinterpret_cast<char*>(As) + c*16);
        }
        #pragma unroll
        for (int i = 0; i < 4; ++i) {
            int c = i*256 + tid;
            int row = c >> 3;
            int kbl = ((c & 7) * 16) ^ ((row & 7) << 4);
            gl_lds16(reinterpret_cast<const char*>(Bt) + ((size_t)(n0+row)*CC + k0)*2 + kbl,
                     reinterpret_cast<char*>(Bs) + c*16);
        }
        __syncthreads();   // drains vmcnt -> tiles ready
        #pragma unroll
        for (int cch = 0; cch < 2; ++cch) {
            bf16x8 a[4], b[4];
            #pragma unroll
            for (int i = 0; i < 4; ++i) {
                int row = wr*64 + i*16 + fr;
                int kph = (cch*64 + g*16) ^ ((row & 7) << 4);
                a[i] = *reinterpret_cast<const bf16x8*>(
                    reinterpret_cast<const char*>(As) + row*128 + kph);
            }
            #pragma unroll
            for (int j = 0; j < 4; ++j) {
                int row = wc*64 + j*16 + fr;
                int kph = (cch*64 + g*16) ^ ((row & 7) << 4);
                b[j] = *reinterpret_cast<const bf16x8*>(
                    reinterpret_cast<const char*>(Bs) + row*128 + kph);
            }
            #pragma unroll
            for (int i = 0; i < 4; ++i)
                #pragma unroll
                for (int j = 0; j < 4; ++j)
                    acc[i][j] = __builtin_amdgcn_mfma_f32_16x16x32_bf16(a[i], b[j], acc[i][j], 0, 0, 0);
        }
    }

    // epilogue: C/D layout col=lane&15, row=(lane>>4)*4+reg
    #pragma unroll
    for (int j = 0; j < 4; ++j) {
        int n = n0 + wc*64 + j*16 + fr;
        float bv = bias[n];
        #pragma unroll
        for (int i = 0; i < 4; ++i) {
            #pragma unroll
            for (int r = 0; r < 4; ++r) {
                int m = m0 + wr*64 + i*16 + g*4 + r;
                float val = (acc[i][j][r] + bv) * scale;
                if (MODE == 0) {
                    int bb = m >> 11, t = m & (TT-1);
                    int h  = n >> 7,  d = n & (HS-1);
                    reinterpret_cast<short*>(dst)[((size_t)(bb*HH + h)*TT + t)*HS + d] = f2bf(val);
                } else if (MODE == 2) {
                    int bb = m >> 11, t = m & (TT-1);
                    int h  = n >> 7,  d = n & (HS-1);
                    reinterpret_cast<short*>(dst)[((size_t)(bb*HH + h)*HS + d)*TT + t] = f2bf(val);
                } else {
                    reinterpret_cast<float*>(dst)[(size_t)m*CC + n] = val;
                }
            }
        }
    }
}

// ---------------- causal flash attention v4 ----------------
// 512 blocks x 256 threads, 48KB LDS -> 3 blocks/CU (whole grid co-resident).
// Single-buffered K/V tiles staged via global_load_lds; per-wave 32 q rows, kv-step 64.
__launch_bounds__(256, 3)
__global__ void attn_kernel(const short* __restrict__ Q, const short* __restrict__ K,
                            const short* __restrict__ Vt, short* __restrict__ O)
{
    __shared__ __align__(16) short Ks[64*128];    // 16KB
    __shared__ __align__(16) short Vs[128*64];    // 16KB
    __shared__ __align__(16) short Ps[4][32*64];  // 16KB

    const int tid = threadIdx.x;
    const int lane = tid & 63;
    const int wid = tid >> 6;
    const int g = lane >> 4, fr = lane & 15;

    // XCD/head locality remap + heavy/light pairing:
    // dd<256 -> heads {0,1} of the XCD group, heavy q-tiles first;
    // dd>=256 -> heads {2,3}, light first. CU pairs (dd, dd+256) balance to 34 steps.
    const int dd = blockIdx.x;          // 0..511
    const int g8 = dd & 7;
    const int i0 = dd >> 3;             // 0..63
    const int bh = g8*4 + (i0 >> 4);
    const int qb = (i0 < 32) ? (15 - (i0 & 15)) : (i0 & 15);
    const int q0 = qb * 128;
    const int wq0 = q0 + wid*32;        // this wave's 32 q rows

    const short* Qh = Q + (size_t)bh * TT * HS;
    const char*  Kg = (const char*)(K  + (size_t)bh * TT * HS);
    const char*  Vg = (const char*)(Vt + (size_t)bh * HS * TT);

    // Q fragments (Q pre-scaled by log2(e)/sqrt(hs))
    bf16x8 qf[2][4];
    #pragma unroll
    for (int qt = 0; qt < 2; ++qt)
        #pragma unroll
        for (int c2 = 0; c2 < 4; ++c2)
            qf[qt][c2] = *reinterpret_cast<const bf16x8*>(
                Qh + (size_t)(wq0 + qt*16 + fr)*HS + c2*32 + g*8);

    f32x4 o[2][8];
    #pragma unroll
    for (int qt = 0; qt < 2; ++qt)
        #pragma unroll
        for (int c = 0; c < 8; ++c) o[qt][c] = (f32x4){0.f,0.f,0.f,0.f};
    float mrun[2][4], lrun[2][4];
    #pragma unroll
    for (int qt = 0; qt < 2; ++qt)
        #pragma unroll
        for (int r = 0; r < 4; ++r) { mrun[qt][r] = -1e30f; lrun[qt][r] = 0.f; }

    char* pw = reinterpret_cast<char*>(Ps[wid]);
    const int nst = q0/64 + 2;

    for (int s2 = 0; s2 < nst; ++s2) {
        const int kv0 = s2 * 64;
        __syncthreads();                        // all waves done reading prev tiles
        // K tile [64 rows x 256B], V tile [128 rows x 128B]: direct global->LDS
        #pragma unroll
        for (int i = 0; i < 4; ++i) {
            int c = i*256 + tid;
            int row = c >> 4;
            int kbl = ((c & 15) * 16) ^ ((row & 7) << 4);
            gl_lds16(Kg + (size_t)(kv0 + row)*256 + kbl, reinterpret_cast<char*>(Ks) + c*16);
        }
        #pragma unroll
        for (int i = 0; i < 4; ++i) {
            int c = i*256 + tid;
            int row = c >> 3;
            int kbl = ((c & 7) * 16) ^ ((row & 7) << 4);
            gl_lds16(Vg + ((size_t)row*TT + kv0)*2 + kbl, reinterpret_cast<char*>(Vs) + c*16);
        }
        __syncthreads();                        // tiles ready

        if (kv0 > wq0 + 31) continue;           // fully-masked step for this wave

        const char* Kl = reinterpret_cast<const char*>(Ks);
        const char* Vl = reinterpret_cast<const char*>(Vs);

        // ---- S = Q K^T ----
        f32x4 s[2][4];
        #pragma unroll
        for (int qt = 0; qt < 2; ++qt)
            #pragma unroll
            for (int h = 0; h < 4; ++h) s[qt][h] = (f32x4){0.f,0.f,0.f,0.f};
        #pragma unroll
        for (int h = 0; h < 4; ++h) {
            bf16x8 kf[4];
            int row = h*16 + fr;
            #pragma unroll
            for (int c2 = 0; c2 < 4; ++c2)
                kf[c2] = *reinterpret_cast<const bf16x8*>(
                    Kl + row*256 + ((c2*64 + g*16) ^ ((row & 7) << 4)));
            #pragma unroll
            for (int c2 = 0; c2 < 4; ++c2) {
                s[0][h] = __builtin_amdgcn_mfma_f32_16x16x32_bf16(qf[0][c2], kf[c2], s[0][h], 0, 0, 0);
                s[1][h] = __builtin_amdgcn_mfma_f32_16x16x32_bf16(qf[1][c2], kf[c2], s[1][h], 0, 0, 0);
            }
        }
        // causal mask (only near the diagonal)
        if (kv0 + 63 > wq0) {
            #pragma unroll
            for (int qt = 0; qt < 2; ++qt)
                #pragma unroll
                for (int h = 0; h < 4; ++h)
                    #pragma unroll
                    for (int r = 0; r < 4; ++r) {
                        int col = kv0 + h*16 + fr;
                        int row = wq0 + qt*16 + g*4 + r;
                        if (col > row) s[qt][h][r] = -1e30f;
                    }
        }
        // ---- online softmax, defer-max (T13): common path has no shuffles, no rescale ----
        #pragma unroll
        for (int qt = 0; qt < 2; ++qt) {
            float pm[4];
            #pragma unroll
            for (int r = 0; r < 4; ++r)
                pm[r] = fmaxf(fmaxf(s[qt][0][r], s[qt][1][r]), fmaxf(s[qt][2][r], s[qt][3][r]));
            bool need = (pm[0] > mrun[qt][0] + 8.f) | (pm[1] > mrun[qt][1] + 8.f) |
                        (pm[2] > mrun[qt][2] + 8.f) | (pm[3] > mrun[qt][3] + 8.f);
            if (__any(need)) {
                #pragma unroll
                for (int off = 1; off < 16; off <<= 1)
                    #pragma unroll
                    for (int r = 0; r < 4; ++r) pm[r] = fmaxf(pm[r], __shfl_xor(pm[r], off));
                float al[4];
                #pragma unroll
                for (int r = 0; r < 4; ++r) {
                    float mn = fmaxf(mrun[qt][r], pm[r]);
                    al[r] = exp2f(mrun[qt][r] - mn);
                    mrun[qt][r] = mn;
                    lrun[qt][r] *= al[r];
                }
                #pragma unroll
                for (int c = 0; c < 8; ++c)
                    #pragma unroll
                    for (int r = 0; r < 4; ++r) o[qt][c][r] *= al[r];
            }
            #pragma unroll
            for (int h = 0; h < 4; ++h)
                #pragma unroll
                for (int r = 0; r < 4; ++r) {
                    float pv = exp2f(s[qt][h][r] - mrun[qt][r]);
                    s[qt][h][r] = pv;
                    lrun[qt][r] += pv;
                }
            // P -> per-wave LDS (swizzled 128B rows)
            #pragma unroll
            for (int h = 0; h < 4; ++h)
                #pragma unroll
                for (int r = 0; r < 4; ++r) {
                    int prow = qt*16 + g*4 + r;
                    int cb   = (h*16 + fr)*2;
                    *reinterpret_cast<short*>(pw + prow*128 + (cb ^ ((prow & 7) << 4))) =
                        f2bf(s[qt][h][r]);
                }
        }
        // ---- O += P * V (both from LDS) ----
        #pragma unroll
        for (int kb = 0; kb < 2; ++kb) {
            bf16x8 pa[2];
            #pragma unroll
            for (int qt = 0; qt < 2; ++qt) {
                int row = qt*16 + fr;
                pa[qt] = *reinterpret_cast<const bf16x8*>(
                    pw + row*128 + ((kb*64 + g*16) ^ ((row & 7) << 4)));
            }
            #pragma unroll
            for (int c = 0; c < 8; ++c) {
                int row = c*16 + fr;
                bf16x8 vf = *reinterpret_cast<const bf16x8*>(
                    Vl + row*128 + ((kb*64 + g*16) ^ ((row & 7) << 4)));
                o[0][c] = __builtin_amdgcn_mfma_f32_16x16x32_bf16(pa[0], vf, o[0][c], 0, 0, 0);
                o[1][c] = __builtin_amdgcn_mfma_f32_16x16x32_bf16(pa[1], vf, o[1][c], 0, 0, 0);
            }
        }
    }

    // final: reduce lane-partial l across 16-lane group, normalize, store
    #pragma unroll
    for (int qt = 0; qt < 2; ++qt)
        #pragma unroll
        for (int off = 1; off < 16; off <<= 1)
            #pragma unroll
            for (int r = 0; r < 4; ++r) lrun[qt][r] += __shfl_xor(lrun[qt][r], off);

    int b = bh >> 4, h = bh & 15;
    #pragma unroll
    for (int qt = 0; qt < 2; ++qt)
        #pragma unroll
        for (int r = 0; r < 4; ++r) {
            int t = wq0 + qt*16 + g*4 + r;
            float inv = 1.f / lrun[qt][r];
            size_t base = ((size_t)(b*TT + t))*CC + (size_t)h*HS;
            #pragma unroll
            for (int c = 0; c < 8; ++c)
                O[base + c*16 + fr] = f2bf(o[qt][c][r] * inv);
        }
}

extern "C" void kernel_launch(void* const* d_in, const int* in_sizes, int n_in,
                              void* d_out, int out_size, void* d_ws, size_t ws_size,
                              hipStream_t stream)
{
    const float* idx = (const float*)d_in[0];
    const float* Wq  = (const float*)d_in[1];
    const float* bq  = (const float*)d_in[2];
    const float* Wk  = (const float*)d_in[3];
    const float* bk  = (const float*)d_in[4];
    const float* Wv  = (const float*)d_in[5];
    const float* bv  = (const float*)d_in[6];
    const float* Wo  = (const float*)d_in[7];
    const float* bo  = (const float*)d_in[8];
    float* out = (float*)d_out;

    short* Xbf = (short*)d_ws;
    short* Wtq = Xbf + (size_t)MM*CC;
    short* Wtk = Wtq + (size_t)CC*CC;
    short* Wtv = Wtk + (size_t)CC*CC;
    short* Wto = Wtv + (size_t)CC*CC;
    short* Qb  = Wto + (size_t)CC*CC;
    short* Kb  = Qb  + (size_t)MM*CC;
    short* Vtb = Kb  + (size_t)MM*CC;
    short* Ob  = Vtb + (size_t)MM*CC;

    cvt_bf16_kernel<<<1024, 256, 0, stream>>>(idx, Xbf, MM*CC);
    wt_kernel<<<dim3(CC/32, CC/32, 4), dim3(32, 8), 0, stream>>>(
        Wq, Wk, Wv, Wo, Wtq, Wtk, Wtv, Wto);

    const float qs = 0.08838834764831845f * 1.4426950408889634f;  // log2(e)/sqrt(128)
    gemm_bt_kernel<0><<<dim3(MM/128, CC/128), 256, 0, stream>>>(Xbf, Wtq, bq, Qb, qs);
    gemm_bt_kernel<0><<<dim3(MM/128, CC/128), 256, 0, stream>>>(Xbf, Wtk, bk, Kb, 1.0f);
    gemm_bt_kernel<2><<<dim3(MM/128, CC/128), 256, 0, stream>>>(Xbf, Wtv, bv, Vtb, 1.0f);

    attn_kernel<<<dim3(512), 256, 0, stream>>>(Qb, Kb, Vtb, Ob);

    gemm_bt_kernel<1><<<dim3(MM/128, CC/128), 256, 0, stream>>>(Ob, Wto, bo, out, 1.0f);
}

// Round 5
// 262.353 us; speedup vs baseline: 1.9406x; 1.9406x over previous
//
#include <hip/hip_runtime.h>
#include <hip/hip_bf16.h>

#define TT 2048
#define CC 2048
#define HH 16
#define HS 128
#define BB 2
#define MM (BB*TT)   // 4096

typedef __attribute__((ext_vector_type(8))) short bf16x8;
typedef __attribute__((ext_vector_type(4))) short bf16x4;
typedef __attribute__((ext_vector_type(4))) float f32x4;
typedef __attribute__((ext_vector_type(16))) float f32x16;

__device__ __forceinline__ short f2bf(float x) {
    unsigned u = __float_as_uint(x);
    unsigned r = (u + 0x7FFFu + ((u >> 16) & 1u)) >> 16;
    return (short)r;
}

// direct global -> LDS async copy, 16B per lane (dest must be wave-uniform base + lane*16)
__device__ __forceinline__ void gl_lds16(const void* g, void* l) {
    __builtin_amdgcn_global_load_lds(
        (const __attribute__((address_space(1))) unsigned int*)g,
        (__attribute__((address_space(3))) unsigned int*)l,
        16, 0, 0);
}

// ---------------- fp32 -> bf16 convert (idx) ----------------
__global__ void cvt_bf16_kernel(const float* __restrict__ x, short* __restrict__ y, int n) {
    int stride = gridDim.x * blockDim.x;
    for (int i = blockIdx.x * blockDim.x + threadIdx.x; i < n/4; i += stride) {
        float4 v = reinterpret_cast<const float4*>(x)[i];
        bf16x4 s;
        s[0] = f2bf(v.x); s[1] = f2bf(v.y); s[2] = f2bf(v.z); s[3] = f2bf(v.w);
        reinterpret_cast<bf16x4*>(y)[i] = s;
    }
}

// ---------------- W [k][n] fp32  ->  Wt [n][k] bf16 ----------------
__global__ void wt_kernel(const float* __restrict__ w0, const float* __restrict__ w1,
                          const float* __restrict__ w2, const float* __restrict__ w3,
                          short* __restrict__ o0, short* __restrict__ o1,
                          short* __restrict__ o2, short* __restrict__ o3)
{
    const float* W; short* Wt;
    switch (blockIdx.z) {
        case 0:  W = w0; Wt = o0; break;
        case 1:  W = w1; Wt = o1; break;
        case 2:  W = w2; Wt = o2; break;
        default: W = w3; Wt = o3; break;
    }
    __shared__ float tile[32][33];
    int tx = threadIdx.x, ty = threadIdx.y;           // block (32,8)
    int k0 = blockIdx.x * 32, n0 = blockIdx.y * 32;
    #pragma unroll
    for (int i = 0; i < 4; ++i)
        tile[ty + i*8][tx] = W[(size_t)(k0 + ty + i*8) * CC + n0 + tx];
    __syncthreads();
    #pragma unroll
    for (int i = 0; i < 4; ++i)
        Wt[(size_t)(n0 + ty + i*8) * CC + k0 + tx] = f2bf(tile[tx][ty + i*8]);
}

// ---------------- GEMM: C[M][N] = A[M][K] * Bt[N][K]^T (+bias, *scale) ----------------
// MODE 0: dst = bf16 [B,H,T,hs] (Q/K);  MODE 1: dst = fp32 [M][N];  MODE 2: dst = bf16 [B,H,hs,T] (V transposed)
template<int MODE>
__launch_bounds__(256)
__global__ void gemm_bt_kernel(const short* __restrict__ A, const short* __restrict__ Bt,
                               const float* __restrict__ bias, void* __restrict__ dst,
                               float scale)
{
    __shared__ __align__(16) short As[128*64];
    __shared__ __align__(16) short Bs[128*64];
    const int tid = threadIdx.x;
    const int lane = tid & 63;
    const int g = lane >> 4, fr = lane & 15;
    const int wid = tid >> 6;
    const int wr = wid >> 1, wc = wid & 1;
    const int m0 = blockIdx.x * 128, n0 = blockIdx.y * 128;

    f32x4 acc[4][4];
    #pragma unroll
    for (int i = 0; i < 4; ++i)
        #pragma unroll
        for (int j = 0; j < 4; ++j) acc[i][j] = (f32x4){0.f,0.f,0.f,0.f};

    for (int k0 = 0; k0 < CC; k0 += 64) {
        __syncthreads();
        #pragma unroll
        for (int i = 0; i < 4; ++i) {
            int c = i*256 + tid;
            int row = c >> 3;
            int kbl = ((c & 7) * 16) ^ ((row & 7) << 4);
            gl_lds16(reinterpret_cast<const char*>(A) + ((size_t)(m0+row)*CC + k0)*2 + kbl,
                     reinterpret_cast<char*>(As) + c*16);
        }
        #pragma unroll
        for (int i = 0; i < 4; ++i) {
            int c = i*256 + tid;
            int row = c >> 3;
            int kbl = ((c & 7) * 16) ^ ((row & 7) << 4);
            gl_lds16(reinterpret_cast<const char*>(Bt) + ((size_t)(n0+row)*CC + k0)*2 + kbl,
                     reinterpret_cast<char*>(Bs) + c*16);
        }
        __syncthreads();
        #pragma unroll
        for (int cch = 0; cch < 2; ++cch) {
            bf16x8 a[4], b[4];
            #pragma unroll
            for (int i = 0; i < 4; ++i) {
                int row = wr*64 + i*16 + fr;
                int kph = (cch*64 + g*16) ^ ((row & 7) << 4);
                a[i] = *reinterpret_cast<const bf16x8*>(
                    reinterpret_cast<const char*>(As) + row*128 + kph);
            }
            #pragma unroll
            for (int j = 0; j < 4; ++j) {
                int row = wc*64 + j*16 + fr;
                int kph = (cch*64 + g*16) ^ ((row & 7) << 4);
                b[j] = *reinterpret_cast<const bf16x8*>(
                    reinterpret_cast<const char*>(Bs) + row*128 + kph);
            }
            #pragma unroll
            for (int i = 0; i < 4; ++i)
                #pragma unroll
                for (int j = 0; j < 4; ++j)
                    acc[i][j] = __builtin_amdgcn_mfma_f32_16x16x32_bf16(a[i], b[j], acc[i][j], 0, 0, 0);
        }
    }

    #pragma unroll
    for (int j = 0; j < 4; ++j) {
        int n = n0 + wc*64 + j*16 + fr;
        float bv = bias[n];
        #pragma unroll
        for (int i = 0; i < 4; ++i) {
            #pragma unroll
            for (int r = 0; r < 4; ++r) {
                int m = m0 + wr*64 + i*16 + g*4 + r;
                float val = (acc[i][j][r] + bv) * scale;
                if (MODE == 0) {
                    int bb = m >> 11, t = m & (TT-1);
                    int h  = n >> 7,  d = n & (HS-1);
                    reinterpret_cast<short*>(dst)[((size_t)(bb*HH + h)*TT + t)*HS + d] = f2bf(val);
                } else if (MODE == 2) {
                    int bb = m >> 11, t = m & (TT-1);
                    int h  = n >> 7,  d = n & (HS-1);
                    reinterpret_cast<short*>(dst)[((size_t)(bb*HH + h)*HS + d)*TT + t] = f2bf(val);
                } else {
                    reinterpret_cast<float*>(dst)[(size_t)m*CC + n] = val;
                }
            }
        }
    }
}

// ---------------- causal flash attention v5: 32x32 MFMA, swapped operands, in-register P ----------------
// 512 blocks x 256 threads (4 waves x 32 q-rows = 128 q/block), kv-step 64.
// K/V double-buffered in LDS via global_load_lds; one __syncthreads per step (loads fly during compute).
__launch_bounds__(256, 2)
__global__ void attn_kernel(const short* __restrict__ Q, const short* __restrict__ K,
                            const short* __restrict__ Vt, short* __restrict__ O)
{
    __shared__ __align__(16) short Ks[2][64*128];   // 2 x 16KB
    __shared__ __align__(16) short Vs[2][128*64];   // 2 x 16KB

    const int tid = threadIdx.x;
    const int lane = tid & 63;
    const int wid = tid >> 6;
    const int l5 = lane >> 5;          // half-wave
    const int q31 = lane & 31;         // this lane's q-row (and K-row / V-row index)
    const bool hif = (l5 != 0);

    // mapping: same-head heavy/light pairing, XCD-grouped heads
    const int dd = blockIdx.x;              // 0..511
    const int g8 = dd & 7;
    const int s  = (dd >> 3) & 31;
    const int half = dd >> 8;               // 0: heavy (dispatched first), 1: light
    const int bh = g8*4 + (s >> 3);         // head 0..31
    const int u  = s & 7;
    const int qb = half ? u : (15 - u);
    const int q0 = qb * 128;
    const int wq0 = q0 + wid*32;            // this wave's 32 q rows

    const short* Qh = Q + (size_t)bh * TT * HS;
    const char*  Kg = (const char*)(K  + (size_t)bh * TT * HS);
    const char*  Vg = (const char*)(Vt + (size_t)bh * HS * TT);

    // Q as B-operand: row = q31, k = dk*16 + l5*8 .. +7   (Q pre-scaled by log2(e)/sqrt(hs))
    bf16x8 qf[8];
    #pragma unroll
    for (int dk = 0; dk < 8; ++dk)
        qf[dk] = *reinterpret_cast<const bf16x8*>(
            Qh + (size_t)(wq0 + q31)*HS + dk*16 + l5*8);

    f32x16 o[4];
    #pragma unroll
    for (int c = 0; c < 4; ++c)
        #pragma unroll
        for (int r = 0; r < 16; ++r) o[c][r] = 0.f;
    float mrun = -1e30f, lrun = 0.f;

    auto stage = [&](int kv0, int p) {
        char* Kd = reinterpret_cast<char*>(Ks[p]);
        char* Vd = reinterpret_cast<char*>(Vs[p]);
        #pragma unroll
        for (int i = 0; i < 4; ++i) {               // K tile: 64 rows x 256B
            int c = i*256 + tid;
            int row = c >> 4;
            int lg  = ((c & 15) * 16) ^ ((row & 7) << 4);
            gl_lds16(Kg + (size_t)(kv0 + row)*256 + lg, Kd + c*16);
        }
        #pragma unroll
        for (int i = 0; i < 4; ++i) {               // Vt tile: 128 rows x 128B
            int c = i*256 + tid;
            int row = c >> 3;
            int lg  = ((c & 7) * 16) ^ ((row & 7) << 4);
            gl_lds16(Vg + ((size_t)row*TT + kv0)*2 + lg, Vd + c*16);
        }
    };

    const int nst = q0/64 + 2;
    stage(0, 0);

    for (int t = 0; t < nst; ++t) {
        const int kv0 = t * 64;
        __syncthreads();                       // drains vmcnt(0): tile t ready everywhere
        if (t + 1 < nst) stage(kv0 + 64, (t+1) & 1);   // next tile flies during compute

        if (kv0 > wq0 + 31) continue;          // fully-masked step for this wave

        const char* Kl = reinterpret_cast<const char*>(Ks[t & 1]);
        const char* Vl = reinterpret_cast<const char*>(Vs[t & 1]);

        // ---- S^T = K Q^T  (swapped: D col = q31, D row = kv-local) ----
        f32x16 st[2];
        #pragma unroll
        for (int t2 = 0; t2 < 2; ++t2)
            #pragma unroll
            for (int r = 0; r < 16; ++r) st[t2][r] = 0.f;
        #pragma unroll
        for (int t2 = 0; t2 < 2; ++t2) {
            int krow = t2*32 + q31;
            int rsw = (krow & 7) << 4;
            #pragma unroll
            for (int dk = 0; dk < 8; ++dk) {
                bf16x8 kf = *reinterpret_cast<const bf16x8*>(
                    Kl + krow*256 + ((dk*32 + l5*16) ^ rsw));
                st[t2] = __builtin_amdgcn_mfma_f32_32x32x16_bf16(kf, qf[dk], st[t2], 0, 0, 0);
            }
        }
        // causal mask (diagonal steps only)
        if (kv0 + 63 > wq0) {
            int qrow = wq0 + q31;
            #pragma unroll
            for (int t2 = 0; t2 < 2; ++t2)
                #pragma unroll
                for (int r = 0; r < 16; ++r) {
                    int kv = kv0 + t2*32 + (r & 3) + ((r >> 2) << 3) + l5*4;
                    if (kv > qrow) st[t2][r] = -1e30f;
                }
        }
        // ---- online softmax: lane owns one q-row; cross-lane only via xor-32 ----
        float pm = -1e30f;
        #pragma unroll
        for (int t2 = 0; t2 < 2; ++t2)
            #pragma unroll
            for (int r = 0; r < 16; ++r) pm = fmaxf(pm, st[t2][r]);
        if (__any(pm > mrun + 8.f)) {          // defer-max: rare rescale
            float pmf = fmaxf(pm, __shfl_xor(pm, 32));
            float mn = fmaxf(mrun, pmf);
            float al = __builtin_amdgcn_exp2f(mrun - mn);
            mrun = mn; lrun *= al;
            #pragma unroll
            for (int c = 0; c < 4; ++c)
                #pragma unroll
                for (int r = 0; r < 16; ++r) o[c][r] *= al;
        }
        float ps = 0.f;
        #pragma unroll
        for (int t2 = 0; t2 < 2; ++t2)
            #pragma unroll
            for (int r = 0; r < 16; ++r) {
                float pv = __builtin_amdgcn_exp2f(st[t2][r] - mrun);
                st[t2][r] = pv;
                ps += pv;
            }
        lrun += ps;
        // ---- pack P to bf16 pairs in-register ----
        unsigned pw[2][8];
        #pragma unroll
        for (int t2 = 0; t2 < 2; ++t2)
            #pragma unroll
            for (int w = 0; w < 8; ++w)
                asm("v_cvt_pk_bf16_f32 %0, %1, %2"
                    : "=v"(pw[t2][w]) : "v"(st[t2][2*w]), "v"(st[t2][2*w+1]));
        // ---- O += V^T P  (A = Vt rows=d, B = P rows=q) ----
        #pragma unroll
        for (int c4 = 0; c4 < 4; ++c4) {
            int t2 = c4 >> 1, b0 = (c4 & 1) * 4;
            unsigned A0 = pw[t2][b0+0], A1 = pw[t2][b0+1];
            unsigned A2 = pw[t2][b0+2], A3 = pw[t2][b0+3];
            unsigned X0 = (unsigned)__shfl_xor((int)A0, 32);
            unsigned X1 = (unsigned)__shfl_xor((int)A1, 32);
            unsigned X2 = (unsigned)__shfl_xor((int)A2, 32);
            unsigned X3 = (unsigned)__shfl_xor((int)A3, 32);
            union { unsigned u[4]; bf16x8 v; } fu;
            fu.u[0] = hif ? X2 : A0;
            fu.u[1] = hif ? X3 : A1;
            fu.u[2] = hif ? A2 : X0;
            fu.u[3] = hif ? A3 : X1;
            #pragma unroll
            for (int c = 0; c < 4; ++c) {
                int vrow = c*32 + q31;
                bf16x8 vf = *reinterpret_cast<const bf16x8*>(
                    Vl + vrow*128 + ((c4*32 + l5*16) ^ ((vrow & 7) << 4)));
                o[c] = __builtin_amdgcn_mfma_f32_32x32x16_bf16(vf, fu.v, o[c], 0, 0, 0);
            }
        }
    }

    // ---- epilogue: one xor-32 reduce for l; store 8B chunks ----
    lrun += __shfl_xor(lrun, 32);
    float inv = 1.f / lrun;
    int b = bh >> 4, h = bh & 15;
    size_t base = ((size_t)(b*TT + wq0 + q31))*CC + (size_t)h*HS;
    #pragma unroll
    for (int c = 0; c < 4; ++c)
        #pragma unroll
        for (int g2 = 0; g2 < 4; ++g2) {
            bf16x4 v4;
            #pragma unroll
            for (int j = 0; j < 4; ++j) v4[j] = f2bf(o[c][g2*4 + j] * inv);
            *reinterpret_cast<bf16x4*>(const_cast<short*>(O) + base + c*32 + g2*8 + l5*4) = v4;
        }
}

extern "C" void kernel_launch(void* const* d_in, const int* in_sizes, int n_in,
                              void* d_out, int out_size, void* d_ws, size_t ws_size,
                              hipStream_t stream)
{
    const float* idx = (const float*)d_in[0];
    const float* Wq  = (const float*)d_in[1];
    const float* bq  = (const float*)d_in[2];
    const float* Wk  = (const float*)d_in[3];
    const float* bk  = (const float*)d_in[4];
    const float* Wv  = (const float*)d_in[5];
    const float* bv  = (const float*)d_in[6];
    const float* Wo  = (const float*)d_in[7];
    const float* bo  = (const float*)d_in[8];
    float* out = (float*)d_out;

    short* Xbf = (short*)d_ws;
    short* Wtq = Xbf + (size_t)MM*CC;
    short* Wtk = Wtq + (size_t)CC*CC;
    short* Wtv = Wtk + (size_t)CC*CC;
    short* Wto = Wtv + (size_t)CC*CC;
    short* Qb  = Wto + (size_t)CC*CC;
    short* Kb  = Qb  + (size_t)MM*CC;
    short* Vtb = Kb  + (size_t)MM*CC;
    short* Ob  = Vtb + (size_t)MM*CC;

    cvt_bf16_kernel<<<1024, 256, 0, stream>>>(idx, Xbf, MM*CC);
    wt_kernel<<<dim3(CC/32, CC/32, 4), dim3(32, 8), 0, stream>>>(
        Wq, Wk, Wv, Wo, Wtq, Wtk, Wtv, Wto);

    const float qs = 0.08838834764831845f * 1.4426950408889634f;  // log2(e)/sqrt(128)
    gemm_bt_kernel<0><<<dim3(MM/128, CC/128), 256, 0, stream>>>(Xbf, Wtq, bq, Qb, qs);
    gemm_bt_kernel<0><<<dim3(MM/128, CC/128), 256, 0, stream>>>(Xbf, Wtk, bk, Kb, 1.0f);
    gemm_bt_kernel<2><<<dim3(MM/128, CC/128), 256, 0, stream>>>(Xbf, Wtv, bv, Vtb, 1.0f);

    attn_kernel<<<dim3(512), 256, 0, stream>>>(Qb, Kb, Vtb, Ob);

    gemm_bt_kernel<1><<<dim3(MM/128, CC/128), 256, 0, stream>>>(Ob, Wto, bo, out, 1.0f);
}